// Round 16
// baseline (470.972 us; speedup 1.0000x reference)
//
#include <hip/hip_runtime.h>
#include <math.h>

#define S 13824          // 24*24*24
#define RT 216           // tokens per region (6^3)
#define SCALE_L2E 0.12751763f   // 128^-0.5 * log2(e): softmax in exp2 domain

// ---------------- 1x1 conv: round-15 v2 (measured win, frozen)
__global__ __launch_bounds__(256) void proj_kernel(
    const float* __restrict__ in, const float* __restrict__ w,
    const float* __restrict__ bias, float* __restrict__ outp, int OC) {
  __shared__ float xs[128][64];
  const int tid = threadIdx.x;
  const int sbase = blockIdx.x * 64;
  for (int i = tid; i < 128 * 64; i += 256)
    xs[i >> 6][i & 63] = in[(size_t)(i >> 6) * S + sbase + (i & 63)];
  __syncthreads();
  const int sl = (tid & 31) * 2;
  const int wv = tid >> 5;
  const int passes = OC >> 6;
  for (int pg = 0; pg < passes; ++pg) {
    const int o = pg * 64 + wv * 8;
    float a[8][2];
#pragma unroll
    for (int r = 0; r < 8; ++r) { a[r][0] = 0.f; a[r][1] = 0.f; }
#pragma unroll 4
    for (int c4 = 0; c4 < 32; ++c4) {
      float2 x0 = *(const float2*)&xs[c4 * 4 + 0][sl];
      float2 x1 = *(const float2*)&xs[c4 * 4 + 1][sl];
      float2 x2 = *(const float2*)&xs[c4 * 4 + 2][sl];
      float2 x3 = *(const float2*)&xs[c4 * 4 + 3][sl];
#pragma unroll
      for (int r = 0; r < 8; ++r) {
        float4 f = ((const float4*)(w + (size_t)(o + r) * 128))[c4];
        a[r][0] += f.x * x0.x + f.y * x1.x + f.z * x2.x + f.w * x3.x;
        a[r][1] += f.x * x0.y + f.y * x1.y + f.z * x2.y + f.w * x3.y;
      }
    }
#pragma unroll
    for (int r = 0; r < 8; ++r) {
      size_t base = (size_t)(o + r) * S + sbase + sl;
      float b = bias[o + r];
      outp[base]     = a[r][0] + b;
      outp[base + 1] = a[r][1] + b;
    }
  }
}

// ---------------- region means (frozen)
__global__ __launch_bounds__(256) void rmean_kernel(
    const float* __restrict__ qk, float* __restrict__ qr, float* __restrict__ kr) {
  const int n = blockIdx.x;
  const int tid = threadIdx.x, lane = tid & 63, wv = tid >> 6;
  const int rh = (n >> 4) * 6, rw = ((n >> 2) & 3) * 6, rd = (n & 3) * 6;
  int soff[4];
#pragma unroll
  for (int i = 0; i < 4; ++i) {
    int vx = lane + i * 64;
    if (vx < RT) {
      int p = vx / 36, qq = (vx / 6) % 6, u = vx % 6;
      soff[i] = (rh + p) * 576 + (rw + qq) * 24 + (rd + u);
    } else soff[i] = -1;
  }
  for (int ci = 0; ci < 64; ++ci) {
    int ch = wv + ci * 4;
    const float* src = qk + (size_t)ch * S;
    float ssum = 0.f;
#pragma unroll
    for (int i = 0; i < 4; ++i)
      if (soff[i] >= 0) ssum += src[soff[i]];
    for (int off = 32; off > 0; off >>= 1)
      ssum += __shfl_xor(ssum, off);
    if (lane == 0) {
      if (ch < 128) qr[n * 128 + ch] = ssum * (1.f / 216.f);
      else          kr[n * 128 + (ch - 128)] = ssum * (1.f / 216.f);
    }
  }
}

// ---------------- routing (frozen)
__global__ __launch_bounds__(64) void route_kernel(
    const float* __restrict__ qr, const float* __restrict__ kr, int* __restrict__ idxb) {
  const int n = blockIdx.x;
  const int t = threadIdx.x;
  float acc = 0.f;
  for (int c = 0; c < 128; ++c) acc += qr[n * 128 + c] * kr[t * 128 + c];
  float val = acc;
  int id = t;
  for (int j = 0; j < 4; ++j) {
    float bv = val;
    int bi = id;
    for (int off = 32; off > 0; off >>= 1) {
      float ov = __shfl_xor(bv, off);
      int oi = __shfl_xor(bi, off);
      if (ov > bv || (ov == bv && oi < bi)) { bv = ov; bi = oi; }
    }
    if (t == 0) idxb[n * 4 + j] = bi;
    if (id == bi) val = -INFINITY;
  }
}

// ---------------- attention v3: float2-paired inner loop (SLP -> v_pk_fma_f32
// candidates: dot 16->8 slots, PV 16->8, rescale 16->8) + exp2-domain softmax
// (SCALE*log2e folded into Q load; exp2f = bare v_exp_f32).
// Staging/swizzle/flash-merge identical to round-14 (measured: FETCH 10.4MB).
__global__ __launch_bounds__(512) void attn_kernel(
    const float* __restrict__ qkv, const int* __restrict__ idxb, float* __restrict__ go) {
  __shared__ __align__(16) float ks[RT][20];
  __shared__ __align__(16) float vs[RT][20];
  const float* q = qkv;
  const float* k = qkv + (size_t)128 * S;
  const float* v = qkv + (size_t)256 * S;
  const int bid = blockIdx.x;
  const int n = bid >> 3, mh = bid & 7;
  const int tid = threadIdx.x;
  const int h = tid >> 8;
  const int qi = tid & 255;
  const int rh = (n >> 4) * 6, rw = ((n >> 2) & 3) * 6, rd = (n & 3) * 6;
  const bool active = qi < RT;

  int slot[7];
#pragma unroll
  for (int s2 = 0; s2 < 7; ++s2) {
    int i = tid + 512 * s2;
    if (i < RT * 16) {
      int t = i % RT, d = i / RT;
      int p = t / 36, qq = (t / 6) % 6, u = t % 6;
      slot[s2] = (d << 20) | (t << 12) | (p * 576 + qq * 24 + u);
    } else slot[s2] = -1;
  }

  float2 ql2[8];
  int sq = 0;
  if (active) {
    int p = qi / 36, qq = (qi / 6) % 6, u = qi % 6;
    sq = (rh + p) * 576 + (rw + qq) * 24 + (rd + u);
    const float* qb = q + (size_t)mh * 16 * S + sq;
#pragma unroll
    for (int i = 0; i < 8; ++i) {
      ql2[i].x = qb[(size_t)(2 * i) * S] * SCALE_L2E;
      ql2[i].y = qb[(size_t)(2 * i + 1) * S] * SCALE_L2E;
    }
  }
  float m = -INFINITY, denom = 0.f;
  float2 o2[8];
#pragma unroll
  for (int i = 0; i < 8; ++i) { o2[i].x = 0.f; o2[i].y = 0.f; }

  for (int j = 0; j < 4; ++j) {
    const int r = idxb[n * 4 + j];
    const int ghb = (r >> 4) * 3456 + ((r >> 2) & 3) * 144 + (r & 3) * 6;
    __syncthreads();
#pragma unroll
    for (int s2 = 0; s2 < 7; ++s2) {
      int sl = slot[s2];
      if (sl >= 0) {
        int d = sl >> 20, t = (sl >> 12) & 255, poff = sl & 4095;
        size_t gidx = (size_t)(mh * 16 + d) * S + ghb + poff;
        ks[t][d] = k[gidx];
        vs[t][d] = v[gidx];
      }
    }
    __syncthreads();
    if (active) {
      for (int key = h * 108; key < h * 108 + 108; ++key) {
        const float4* kp = (const float4*)&ks[key][0];
        float4 ka = kp[0], kb = kp[1], kc = kp[2], kd = kp[3];
        // two paired accumulators, 4-deep chains, pk-fma friendly
        float2 dpa, dpb;
        dpa.x = ql2[0].x * ka.x;           dpa.y = ql2[0].y * ka.y;
        dpb.x = ql2[2].x * kb.x;           dpb.y = ql2[2].y * kb.y;
        dpa.x = fmaf(ql2[1].x, ka.z, dpa.x); dpa.y = fmaf(ql2[1].y, ka.w, dpa.y);
        dpb.x = fmaf(ql2[3].x, kb.z, dpb.x); dpb.y = fmaf(ql2[3].y, kb.w, dpb.y);
        dpa.x = fmaf(ql2[4].x, kc.x, dpa.x); dpa.y = fmaf(ql2[4].y, kc.y, dpa.y);
        dpb.x = fmaf(ql2[6].x, kd.x, dpb.x); dpb.y = fmaf(ql2[6].y, kd.y, dpb.y);
        dpa.x = fmaf(ql2[5].x, kc.z, dpa.x); dpa.y = fmaf(ql2[5].y, kc.w, dpa.y);
        dpb.x = fmaf(ql2[7].x, kd.z, dpb.x); dpb.y = fmaf(ql2[7].y, kd.w, dpb.y);
        float dot = (dpa.x + dpa.y) + (dpb.x + dpb.y);
        if (dot > m) {
          float rsc = exp2f(m - dot);
          denom *= rsc;
#pragma unroll
          for (int i = 0; i < 8; ++i) { o2[i].x *= rsc; o2[i].y *= rsc; }
          m = dot;
        }
        float p = exp2f(dot - m);
        denom += p;
        const float4* vp = (const float4*)&vs[key][0];
        float4 va = vp[0], vb = vp[1], vc = vp[2], vd = vp[3];
        o2[0].x = fmaf(p, va.x, o2[0].x); o2[0].y = fmaf(p, va.y, o2[0].y);
        o2[1].x = fmaf(p, va.z, o2[1].x); o2[1].y = fmaf(p, va.w, o2[1].y);
        o2[2].x = fmaf(p, vb.x, o2[2].x); o2[2].y = fmaf(p, vb.y, o2[2].y);
        o2[3].x = fmaf(p, vb.z, o2[3].x); o2[3].y = fmaf(p, vb.w, o2[3].y);
        o2[4].x = fmaf(p, vc.x, o2[4].x); o2[4].y = fmaf(p, vc.y, o2[4].y);
        o2[5].x = fmaf(p, vc.z, o2[5].x); o2[5].y = fmaf(p, vc.w, o2[5].y);
        o2[6].x = fmaf(p, vd.x, o2[6].x); o2[6].y = fmaf(p, vd.y, o2[6].y);
        o2[7].x = fmaf(p, vd.z, o2[7].x); o2[7].y = fmaf(p, vd.w, o2[7].y);
      }
    }
  }
  // flash-merge the two key-halves (exp2 domain)
  __syncthreads();
  float* mb = (float*)ks;
  if (h == 1 && active) {
    mb[qi * 18 + 0] = m;
    mb[qi * 18 + 1] = denom;
#pragma unroll
    for (int i = 0; i < 8; ++i) {
      mb[qi * 18 + 2 + 2 * i]     = o2[i].x;
      mb[qi * 18 + 2 + 2 * i + 1] = o2[i].y;
    }
  }
  __syncthreads();
  if (h == 0 && active) {
    float m1 = mb[qi * 18 + 0], d1 = mb[qi * 18 + 1];
    float M = fmaxf(m, m1);
    float s0 = exp2f(m - M), s1 = exp2f(m1 - M);
    float inv = 1.f / (denom * s0 + d1 * s1);
    float* gb = go + (size_t)mh * 16 * S + sq;
#pragma unroll
    for (int i = 0; i < 8; ++i) {
      gb[(size_t)(2 * i) * S]     = (o2[i].x * s0 + mb[qi * 18 + 2 + 2 * i]     * s1) * inv;
      gb[(size_t)(2 * i + 1) * S] = (o2[i].y * s0 + mb[qi * 18 + 2 + 2 * i + 1] * s1) * inv;
    }
  }
}

// ---------------- lepe: round-15 v2 (measured win, frozen)
__global__ __launch_bounds__(192) void lepe_kernel(
    const float* __restrict__ v, const float* __restrict__ wl,
    const float* __restrict__ bl, float* __restrict__ go) {
  const int c = blockIdx.y;
  const int hw = blockIdx.x * 192 + threadIdx.x;
  const int h = hw / 24, w = hw % 24;
  const float* vp = v + (size_t)c * S;
  float wreg[27];
#pragma unroll
  for (int i = 0; i < 27; ++i) wreg[i] = wl[c * 27 + i];
  const float bc = bl[c];
  float win[9][3];
#pragma unroll
  for (int ab = 0; ab < 9; ++ab) {
    int hh = h + ab / 3 - 1, ww = w + ab % 3 - 1;
    bool ok = (hh >= 0 && hh < 24 && ww >= 0 && ww < 24);
    const float* rp = vp + hh * 576 + ww * 24;
    win[ab][0] = 0.f;
    win[ab][1] = ok ? rp[0] : 0.f;
    win[ab][2] = ok ? rp[1] : 0.f;
  }
  size_t obase = (size_t)c * S + h * 576 + w * 24;
  for (int d = 0; d < 24; ++d) {
    float acc = bc;
#pragma unroll
    for (int ab = 0; ab < 9; ++ab)
      acc += win[ab][0] * wreg[ab * 3 + 0]
           + win[ab][1] * wreg[ab * 3 + 1]
           + win[ab][2] * wreg[ab * 3 + 2];
    go[obase + d] += acc;
    int nd = d + 2;
#pragma unroll
    for (int ab = 0; ab < 9; ++ab) {
      win[ab][0] = win[ab][1];
      win[ab][1] = win[ab][2];
      int hh = h + ab / 3 - 1, ww = w + ab % 3 - 1;
      bool ok = (hh >= 0 && hh < 24 && ww >= 0 && ww < 24 && nd < 24);
      win[ab][2] = ok ? vp[hh * 576 + ww * 24 + nd] : 0.f;
    }
  }
}

extern "C" void kernel_launch(void* const* d_in, const int* in_sizes, int n_in,
                              void* d_out, int out_size, void* d_ws, size_t ws_size,
                              hipStream_t stream) {
  const float* x      = (const float*)d_in[0];
  const float* w_qkv  = (const float*)d_in[1];
  const float* b_qkv  = (const float*)d_in[2];
  const float* w_lepe = (const float*)d_in[3];
  const float* b_lepe = (const float*)d_in[4];
  const float* w_out  = (const float*)d_in[5];
  const float* b_out  = (const float*)d_in[6];
  float* out = (float*)d_out;
  float* ws  = (float*)d_ws;

  float* qkv  = ws;                        // 384*13824
  float* go   = qkv + (size_t)384 * S;     // 128*13824
  float* qr   = go + (size_t)128 * S;      // 64*128
  float* kr   = qr + 8192;                 // 64*128
  int*   idxb = (int*)(kr + 8192);         // 64*4

  proj_kernel<<<216, 256, 0, stream>>>(x, w_qkv, b_qkv, qkv, 384);
  rmean_kernel<<<64, 256, 0, stream>>>(qkv, qr, kr);
  route_kernel<<<64, 64, 0, stream>>>(qr, kr, idxb);
  attn_kernel<<<512, 512, 0, stream>>>(qkv, idxb, go);
  lepe_kernel<<<dim3(3, 128), 192, 0, stream>>>(qkv + (size_t)256 * S, w_lepe, b_lepe, go);
  proj_kernel<<<216, 256, 0, stream>>>(go, w_out, b_out, out, 128);
}